// Round 6
// baseline (146.158 us; speedup 1.0000x reference)
//
#include <hip/hip_runtime.h>

typedef __bf16   bf16x8 __attribute__((ext_vector_type(8)));
typedef float    f32x4  __attribute__((ext_vector_type(4)));
typedef float    f32x2  __attribute__((ext_vector_type(2)));
typedef uint32_t u32x4  __attribute__((ext_vector_type(4)));

constexpr int N_ = 16384;
constexpr int D_ = 16;
constexpr int P_ = 8;
constexpr int H_ = 128;
constexpr int M_ = 50;

// prologue-only pack (round-half-up; matches the weight quantization of all
// passing rounds)
__device__ __forceinline__ uint32_t pk_bf16(float a, float b) {
    uint32_t ua = __builtin_bit_cast(uint32_t, a) + 0x8000u;
    uint32_t ub = __builtin_bit_cast(uint32_t, b) + 0x8000u;
    return __builtin_amdgcn_perm(ub, ua, 0x07060302u);   // low=a, high=b
}
// in-loop pack: single-instruction packed convert (RNE; validated R7/R8)
__device__ __forceinline__ uint32_t cvtpk(float a, float b) {
    uint32_t r;
    asm("v_cvt_pk_bf16_f32 %0, %1, %2" : "=v"(r) : "v"(a), "v"(b));
    return r;
}
__device__ __forceinline__ uint32_t cvtpk_relu(float a, float b) {
    return cvtpk(fmaxf(a, 0.0f), fmaxf(b, 0.0f));
}

// R9 = R7 (time-split, 2 waves/SIMD, w2-in-reg + w1/w3/b2/b3-in-LDS) with the
// ~30 regs that caused R7's marginal spill removed:
//  - sched_barrier(0) between prologue fragment builds (cap transient spike;
//    VGPR max is over the whole kernel, and R7's unrolled 128-load W2
//    prologue was a pressure peak)
//  - noise prefetch distance 2 -> 1; b3 C-in read from LDS per step;
//    replay unroll 5 -> 2; no cross-step pipeline (worthless at 1 wave, R8)
//  - ANTI-HOIST guard: empty asm redefines the LDS byte-offsets each
//    iteration so the loop-invariant LDS weight reads can't be promoted to
//    registers (suspected source of R7's hidden +40 regs). Pointer provenance
//    (addrspace 3) is untouched -- only the integer offset is opaque.
// Rationale: per-SIMD MFMA floor is ~650-850 cyc/step (MfmaUtil 24% x 2690 =
// 645 matches); measured 2690 -> ~1400 cyc/step of single-wave dependency
// stall that only a SECOND RESIDENT WAVE can absorb. 2 waves need <=256
// unified regs/wave. Ledger: w2f 128 + h1b/h2b/h2c 48 + state ~30 + LDS-read
// temps ~24 + slack ~= 235.
// GATE: WRITE_SIZE ~= 1.1 MB (output only). Spill => direction dead.
__global__ __launch_bounds__(128, 2)
void sde_fused(const float* __restrict__ X0,
               const float* __restrict__ V0,
               const float* __restrict__ Yobs,
               const float* __restrict__ noise,
               const float* __restrict__ W1, const float* __restrict__ b1,
               const float* __restrict__ W2, const float* __restrict__ b2,
               const float* __restrict__ W3, const float* __restrict__ b3,
               float* __restrict__ out)
{
    const int tid  = threadIdx.x;
    const int lane = tid & 63;
    const int half = tid >> 6;           // 0: steps 0..24, 1: steps 25..49
    const int n    = lane & 15;
    const int q    = lane >> 4;
    const int gr   = blockIdx.x * 16 + n;

    const float dt   = 0.02f;
    const float sqdt = 0.1414213562373095f;

    // LDS layout (bytes): w1 frags [8][64]x16 @ 0 ; w3 frags [4][64]x16 @ 8192
    //                     b2[128]f @ 12288 ; b3[16]f @ 12800 ; vpart[16]f @ 12864
    __shared__ __align__(16) unsigned char smem[12928];

    // ---- prologue: wave 0 stages LDS-resident operands ----
    if (half == 0) {
#pragma unroll
        for (int ct = 0; ct < 8; ++ct) {
            u32x4 u;
            u[0] = pk_bf16(W1[(1 + q * 4 + 0) * H_ + ct * 16 + n],
                           W1[(1 + q * 4 + 1) * H_ + ct * 16 + n]);
            u[1] = pk_bf16(W1[(1 + q * 4 + 2) * H_ + ct * 16 + n],
                           W1[(1 + q * 4 + 3) * H_ + ct * 16 + n]);
            u[2] = pk_bf16(W1[(17 + q * 2 + 0) * H_ + ct * 16 + n],
                           W1[(17 + q * 2 + 1) * H_ + ct * 16 + n]);
            u[3] = (q == 0) ? pk_bf16(b1[ct * 16 + n], W1[ct * 16 + n]) : 0u;
            *(bf16x8*)(smem + ct * 1024 + lane * 16) = __builtin_bit_cast(bf16x8, u);
            __builtin_amdgcn_sched_barrier(0);
        }
#pragma unroll
        for (int kt = 0; kt < 4; ++kt) {
            u32x4 u;
#pragma unroll
            for (int w = 0; w < 4; ++w) {
                int h0 = (kt * 2 + (w >> 1)) * 16 + q * 4 + (w & 1) * 2;
                u[w] = pk_bf16(W3[h0 * D_ + n], W3[(h0 + 1) * D_ + n]);
            }
            *(bf16x8*)(smem + 8192 + kt * 1024 + lane * 16) = __builtin_bit_cast(bf16x8, u);
            __builtin_amdgcn_sched_barrier(0);
        }
        if (lane < 32) *(f32x4*)(smem + 12288 + lane * 16) = *(const f32x4*)&b2[lane * 4];
        if (lane < 4)  *(f32x4*)(smem + 12800 + lane * 16) = *(const f32x4*)&b3[lane * 4];
    }

    // ---- w2f: register-resident in both waves (the only big resident set) ----
    bf16x8 w2f[8][4];
#pragma unroll
    for (int ct = 0; ct < 8; ++ct) {
#pragma unroll
        for (int kt = 0; kt < 4; ++kt) {
            u32x4 u;
#pragma unroll
            for (int w = 0; w < 4; ++w) {
                int h0 = (kt * 2 + (w >> 1)) * 16 + q * 4 + (w & 1) * 2;
                u[w] = pk_bf16(W2[h0 * H_ + ct * 16 + n],
                               W2[(h0 + 1) * H_ + ct * 16 + n]);
            }
            w2f[ct][kt] = __builtin_bit_cast(bf16x8, u);
        }
        __builtin_amdgcn_sched_barrier(0);   // cap prologue register spike
    }

    __syncthreads();   // one-time: LDS weights ready

    // ---- state ----
    f32x4 x = *(const f32x4*)&X0[gr * D_ + q * 4];
    f32x2 y2 = *(const f32x2*)&Yobs[gr * P_ + q * 2];
    const uint32_t yw = pk_bf16(y2[0], y2[1]);
    const float* npb = noise + (size_t)gr * D_ + q * 4;

    // ---- wave 1: bit-exact replay of the X recurrence through steps 0..24 ----
    if (half == 1) {
#pragma unroll 2
        for (int m = 0; m < 25; ++m) {
            f32x4 e = *(const f32x4*)(npb + (size_t)m * N_ * D_);
#pragma unroll
            for (int r = 0; r < 4; ++r)
                x[r] = fmaf(x[r], 0.98f, sqdt * e[r]);
        }
    }

    const int s0 = half * 25;
    float t = half ? 0.5f : 0.0f;        // 25*dt == 0.5 (verified handoff)
    f32x4 e0 = *(const f32x4*)(npb + (size_t)s0 * N_ * D_);
    float vacc = 0.0f;

    uint32_t lofs = (uint32_t)lane * 16u;   // per-lane LDS byte offset
    uint32_t qofs = (uint32_t)q * 16u;      // per-qgroup LDS byte offset

#pragma unroll 1
    for (int i = 0; i < 25; ++i) {
        // opacify LDS offsets: blocks cross-iteration promotion of the
        // weight reads into registers (pointer provenance stays LDS)
        asm volatile("" : "+v"(lofs), "+v"(qofs));

        const int m  = s0 + i;
        const int mn = (m + 1 < M_) ? (m + 1) : (M_ - 1);
        f32x4 e1 = *(const f32x4*)(npb + (size_t)mn * N_ * D_);

        // ---- layer 1 B fragment: [X(4) | Y(2) | one | t] ----
        u32x4 au;
        au[0] = cvtpk(x[0], x[1]);
        au[1] = cvtpk(x[2], x[3]);
        au[2] = yw;
        au[3] = (q == 0) ? cvtpk(1.0f, t) : 0u;
        bf16x8 a0 = __builtin_bit_cast(bf16x8, au);

        // ---- layer 1: stream w1 fragments from LDS ----
        bf16x8 h1b[4];
#pragma unroll
        for (int kt = 0; kt < 4; ++kt) {
            bf16x8 wa = *(const bf16x8*)(smem + (2 * kt) * 1024 + lofs);
            bf16x8 wb = *(const bf16x8*)(smem + (2 * kt + 1) * 1024 + lofs);
            f32x4 ha = __builtin_amdgcn_mfma_f32_16x16x32_bf16(
                wa, a0, (f32x4){0.f, 0.f, 0.f, 0.f}, 0, 0, 0);
            f32x4 hb = __builtin_amdgcn_mfma_f32_16x16x32_bf16(
                wb, a0, (f32x4){0.f, 0.f, 0.f, 0.f}, 0, 0, 0);
            u32x4 u;
            u[0] = cvtpk_relu(ha[0], ha[1]);
            u[1] = cvtpk_relu(ha[2], ha[3]);
            u[2] = cvtpk_relu(hb[0], hb[1]);
            u[3] = cvtpk_relu(hb[2], hb[3]);
            h1b[kt] = __builtin_bit_cast(bf16x8, u);
        }

        // ---- layer 2: two 4-wide batches; C-in = b2 broadcast from LDS ----
        bf16x8 h2b[4];
        {
            f32x4 h2c[4];
#pragma unroll
            for (int cc = 0; cc < 4; ++cc) {
                f32x4 c = *(const f32x4*)(smem + 12288 + cc * 64 + qofs);
#pragma unroll
                for (int kt = 0; kt < 4; ++kt)
                    c = __builtin_amdgcn_mfma_f32_16x16x32_bf16(
                        w2f[cc][kt], h1b[kt], c, 0, 0, 0);
                h2c[cc] = c;
            }
#pragma unroll
            for (int j = 0; j < 2; ++j) {
                u32x4 u;
                u[0] = cvtpk_relu(h2c[2 * j][0], h2c[2 * j][1]);
                u[1] = cvtpk_relu(h2c[2 * j][2], h2c[2 * j][3]);
                u[2] = cvtpk_relu(h2c[2 * j + 1][0], h2c[2 * j + 1][1]);
                u[3] = cvtpk_relu(h2c[2 * j + 1][2], h2c[2 * j + 1][3]);
                h2b[j] = __builtin_bit_cast(bf16x8, u);
            }
        }
        {
            f32x4 h2c[4];
#pragma unroll
            for (int cc = 0; cc < 4; ++cc) {
                f32x4 c = *(const f32x4*)(smem + 12288 + (cc + 4) * 64 + qofs);
#pragma unroll
                for (int kt = 0; kt < 4; ++kt)
                    c = __builtin_amdgcn_mfma_f32_16x16x32_bf16(
                        w2f[cc + 4][kt], h1b[kt], c, 0, 0, 0);
                h2c[cc] = c;
            }
#pragma unroll
            for (int j = 0; j < 2; ++j) {
                u32x4 u;
                u[0] = cvtpk_relu(h2c[2 * j][0], h2c[2 * j][1]);
                u[1] = cvtpk_relu(h2c[2 * j][2], h2c[2 * j][3]);
                u[2] = cvtpk_relu(h2c[2 * j + 1][0], h2c[2 * j + 1][1]);
                u[3] = cvtpk_relu(h2c[2 * j + 1][2], h2c[2 * j + 1][3]);
                h2b[2 + j] = __builtin_bit_cast(bf16x8, u);
            }
        }

        // ---- layer 3: w3 + b3 streamed from LDS ----
        f32x4 b3c = *(const f32x4*)(smem + 12800 + qofs);
        bf16x8 w3a = *(const bf16x8*)(smem + 8192 + 0 * 1024 + lofs);
        bf16x8 w3b = *(const bf16x8*)(smem + 8192 + 1 * 1024 + lofs);
        f32x4 za = __builtin_amdgcn_mfma_f32_16x16x32_bf16(w3a, h2b[0], b3c, 0, 0, 0);
        za = __builtin_amdgcn_mfma_f32_16x16x32_bf16(w3b, h2b[1], za, 0, 0, 0);
        bf16x8 w3c = *(const bf16x8*)(smem + 8192 + 2 * 1024 + lofs);
        bf16x8 w3d = *(const bf16x8*)(smem + 8192 + 3 * 1024 + lofs);
        f32x4 zb = __builtin_amdgcn_mfma_f32_16x16x32_bf16(
            w3c, h2b[2], (f32x4){0.f, 0.f, 0.f, 0.f}, 0, 0, 0);
        zb = __builtin_amdgcn_mfma_f32_16x16x32_bf16(w3d, h2b[3], zb, 0, 0, 0);

        // ---- V partial + X update ----
#pragma unroll
        for (int r = 0; r < 4; ++r) {
            float z  = za[r] + zb[r];
            float wn = sqdt * e0[r];
            vacc = fmaf(z, wn, fmaf(0.01f * z, z, vacc));   // z*wn + dt/2*z^2
            x[r] = fmaf(x[r], 0.98f, wn);                   // (1-dt)*x + wn
        }

        e0 = e1;
        t += dt;
    }

    // ---- V reduction across the 4 q-groups within each wave ----
    float part = vacc;
    part += __shfl_xor(part, 16);
    part += __shfl_xor(part, 32);

    // ---- combine the two time-halves (single end-of-kernel barrier) ----
    if (half == 0 && q == 0) *(float*)(smem + 12864 + n * 4) = part;
    __syncthreads();
    if (half == 1) {
        *(f32x4*)&out[gr * D_ + q * 4] = x;                 // final X (step 50)
        if (q == 0)
            out[N_ * D_ + gr] = V0[gr] + *(const float*)(smem + 12864 + n * 4) + part;
    }
}

extern "C" void kernel_launch(void* const* d_in, const int* in_sizes, int n_in,
                              void* d_out, int out_size, void* d_ws, size_t ws_size,
                              hipStream_t stream)
{
    const float* X0 = (const float*)d_in[0];
    const float* V0 = (const float*)d_in[1];
    const float* Y  = (const float*)d_in[2];
    const float* nz = (const float*)d_in[3];
    const float* W1 = (const float*)d_in[4];
    const float* b1 = (const float*)d_in[5];
    const float* W2 = (const float*)d_in[6];
    const float* b2 = (const float*)d_in[7];
    const float* W3 = (const float*)d_in[8];
    const float* b3 = (const float*)d_in[9];
    float* out = (float*)d_out;

    sde_fused<<<N_ / 16, 128, 0, stream>>>(X0, V0, Y, nz, W1, b1, W2, b2, W3, b3, out);
}